// Round 9
// baseline (183.079 us; speedup 1.0000x reference)
//
#include <hip/hip_runtime.h>

#define B_   4
#define T_   2048
#define E_   512
#define D_   512
#define N_   16
#define L_   4
#define TCH  32          // elements per lane — a lane owns 32 contiguous t

typedef __bf16 bf16x8 __attribute__((ext_vector_type(8)));
typedef float  f32x4  __attribute__((ext_vector_type(4)));
typedef float  f32x2  __attribute__((ext_vector_type(2)));
typedef unsigned short us8 __attribute__((ext_vector_type(8)));

__device__ __forceinline__ float us2f(unsigned short u) {
    return __uint_as_float(((unsigned int)u) << 16);
}
__device__ __forceinline__ unsigned short f2us(float f) {
    unsigned int u = __float_as_uint(f);
    unsigned int r = (u + 0x7fffu + ((u >> 16) & 1u)) >> 16;   // RNE
    return (unsigned short)r;
}
__device__ __forceinline__ float ldin(const void* p, int i, unsigned int f) {
    return f ? ((const float*)p)[i] : us2f(((const unsigned short*)p)[i]);
}
__device__ __forceinline__ unsigned int probe_f32(const void* lnfs) {
    return (((const unsigned int*)lnfs)[0] == 0x3F800000u) ? 1u : 0u;
}
__device__ __forceinline__ f32x2 pk_fma(f32x2 a, f32x2 b, f32x2 c) {
    f32x2 d;
    asm("v_pk_fma_f32 %0, %1, %2, %3" : "=v"(d) : "v"(a), "v"(b), "v"(c));
    return d;
}
// masked-row DPP (0x142/0x143): masked lanes must yield 0 for the fma — old=0 form
template<int CTRL, int RM>
__device__ __forceinline__ f32x2 dpp2(f32x2 v) {
    f32x2 r;
    r[0] = __int_as_float(__builtin_amdgcn_update_dpp(0, __float_as_int(v[0]), CTRL, RM, 0xF, true));
    r[1] = __int_as_float(__builtin_amdgcn_update_dpp(0, __float_as_int(v[1]), CTRL, RM, 0xF, true));
    return r;
}
// full-mask DPP: single v_mov_b32_dpp, bound_ctrl zero-fills invalid lanes
template<int CTRL>
__device__ __forceinline__ f32x2 mdpp2(f32x2 v) {
    f32x2 r;
    r[0] = __int_as_float(__builtin_amdgcn_mov_dpp(__float_as_int(v[0]), CTRL, 0xF, 0xF, true));
    r[1] = __int_as_float(__builtin_amdgcn_mov_dpp(__float_as_int(v[1]), CTRL, 0xF, 0xF, true));
    return r;
}

// canonical param block offsets (floats)
#define PA    0
#define PB    32768
#define PC    65536
#define PDT   98304
#define PDSK  100352
#define PLFS  102400
#define PLFB  102912
#define PWF   103424
#define PLES  103936
#define PLEB  104448
#define PWEN  104960
#define PSC   105472   // [0]=b_f0, [1]=b_en
#define PRM_N 105474

#define NB_TEXT 2048
#define NB_PRM  413       // ceil(PRM_N/256)
#define NB_WT   64        // 8x8 tiles of 64x64
#define NB_S4P  128       // L*D*N/256 — precomputed scan params

// ---------------- prep: text->bf16, params->fp32 P, Wt transpose, S4 param precompute ----------------
__global__ __launch_bounds__(256) void prep_kernel(
    const void* X, const void* Win,
    const void* A_log, const void* B_ssm, const void* C_ssm,
    const void* log_dt, const void* D_skip,
    const void* lnfs, const void* lnfb, const void* Wf0,
    const void* lnes, const void* lneb, const void* Wen,
    const void* bf0, const void* ben,
    unsigned short* __restrict__ textc, unsigned short* __restrict__ Wt,
    float* __restrict__ P, float* __restrict__ P2, float* __restrict__ PW) {
    __shared__ float tile[64 * 65];
    unsigned int f = probe_f32(lnfs);
    int bid = blockIdx.x;
    if (bid < NB_TEXT) {
        int i = (bid * 256 + threadIdx.x) * 8;
        if (f) {
            const float* xf = (const float*)X;
            us8 r;
#pragma unroll
            for (int j = 0; j < 8; j++) r[j] = f2us(xf[i + j]);
            *(us8*)(textc + i) = r;
        } else {
            *(us8*)(textc + i) = *(const us8*)((const unsigned short*)X + i);
        }
    } else if (bid < NB_TEXT + NB_PRM) {
        int i = (bid - NB_TEXT) * 256 + threadIdx.x;
        if      (i < PB)     P[i] = ldin(A_log,  i - PA,   f);
        else if (i < PC)     P[i] = ldin(B_ssm,  i - PB,   f);
        else if (i < PDT)    P[i] = ldin(C_ssm,  i - PC,   f);
        else if (i < PDSK)   P[i] = ldin(log_dt, i - PDT,  f);
        else if (i < PLFS)   P[i] = ldin(D_skip, i - PDSK, f);
        else if (i < PLFB)   P[i] = ldin(lnfs,   i - PLFS, f);
        else if (i < PWF)    P[i] = ldin(lnfb,   i - PLFB, f);
        else if (i < PLES)   P[i] = ldin(Wf0,    i - PWF,  f);
        else if (i < PLEB)   P[i] = ldin(lnes,   i - PLES, f);
        else if (i < PWEN)   P[i] = ldin(lneb,   i - PLEB, f);
        else if (i < PSC)    P[i] = ldin(Wen,    i - PWEN, f);
        else if (i == PSC)     P[i] = ldin(bf0, 0, f);
        else if (i == PSC + 1) P[i] = ldin(ben, 0, f);
    } else if (bid < NB_TEXT + NB_PRM + NB_WT) {
        // Wt[d][e] = W_in[e][d]  (bf16 out), 64x64 LDS tile
        int tb = bid - (NB_TEXT + NB_PRM);
        int d0 = (tb >> 3) * 64, e0 = (tb & 7) * 64;
        int r = threadIdx.x >> 6, i = threadIdx.x & 63;
#pragma unroll
        for (int k = 0; k < 16; k++) {
            int e = k * 4 + r;
            tile[e * 65 + i] = ldin(Win, (e0 + e) * D_ + d0 + i, f);
        }
        __syncthreads();
#pragma unroll
        for (int k = 0; k < 16; k++) {
            int dd = k * 4 + r;
            Wt[(size_t)(d0 + dd) * E_ + e0 + i] = f2us(tile[i * 65 + dd]);
        }
    } else {
        // S4 param precompute: i indexes (l,d,n); per (l,d) P2 layout (stride 32):
        //   [Ab16 | CB16]
        // z'-space scan (z' = z/CB): state update is one FMA; CB applied in y-sum.
        // Chunk length 32 (one lane owns 32 t) -> M = Ab^32.
        // PW power table: PW[ld*1024 + k*16 + n] = M^k. s4 only reads k<=32
        // (stage weights 1,2,4,8; w1<=16; w2<=32) -> write 33 entries, not 64.
        int i = (bid - (NB_TEXT + NB_PRM + NB_WT)) * 256 + threadIdx.x;   // [0, L*D*N)
        int n = i & 15;
        int ld = i >> 4;                       // l*512 + d
        float dt = __expf(ldin(log_dt, ld, f));
        float A  = -__expf(ldin(A_log, i, f));
        float Ab = __expf(dt * A);
        float Bb = (Ab - 1.f) / A * ldin(B_ssm, i, f);
        float l2M = 46.166241308446827f * dt * A;   // log2(Ab^32) = 32*dt*A/ln2
        float M   = exp2f(l2M);                     // M = Ab^32
        int base = ld * 32 + n;
        P2[base]      = Ab;
        P2[base + 16] = Bb * ldin(C_ssm, i, f);     // CB
        float pw = 1.f;
        size_t pb = ((size_t)ld << 10) + n;
#pragma unroll
        for (int k = 0; k < 33; k++) { PW[pb + (k << 4)] = pw; pw *= M; }
    }
}

// ---------------- GEMM: H[b][d][t] = sum_e X[b][t][e]*W_in[e][d] + freq[t][d] + b_in[d] ----------------
// R20 (kept): 64x64 tiles, 1024 blocks = 4 blocks/CU = 4 waves/SIMD.
__global__ __launch_bounds__(256) void gemm_kernel(const unsigned short* __restrict__ X,
                                                   const unsigned short* __restrict__ Wt,
                                                   const void* __restrict__ freq,
                                                   const void* __restrict__ b_in,
                                                   const void* __restrict__ lnfs,
                                                   float* __restrict__ H) {
    __shared__ unsigned short wlds[64 * 264];
    const unsigned int fl = probe_f32(lnfs);
    const int tid = threadIdx.x;
    const int w  = tid >> 6;
    const int ln = tid & 15;
    const int q  = (tid >> 4) & 3;
    const int d0 = blockIdx.x * 64;
    const int t0 = blockIdx.y * 64;
    const int b  = blockIdx.z;

    f32x4 acc[4];
#pragma unroll
    for (int j = 0; j < 4; j++) { acc[j][0]=0.f; acc[j][1]=0.f; acc[j][2]=0.f; acc[j][3]=0.f; }

    const size_t xbase = ((size_t)b * T_ + t0) * E_;

#pragma unroll
    for (int p = 0; p < 2; ++p) {
        if (p) __syncthreads();
#pragma unroll
        for (int it = 0; it < 8; ++it) {
            int flat = it * 256 + tid;
            int d = flat >> 5;
            int e = (flat & 31) << 3;
            bf16x8 v = *(const bf16x8*)(Wt + (size_t)(d0 + d) * E_ + p * 256 + e);
            *(bf16x8*)(wlds + d * 264 + e) = v;
        }
        __syncthreads();
#pragma unroll
        for (int s = 0; s < 8; ++s) {
            const int eo = s * 32 + q * 8;
            bf16x8 bfr[4];
#pragma unroll
            for (int j = 0; j < 4; j++)
                bfr[j] = *(const bf16x8*)(wlds + (j * 16 + ln) * 264 + eo);
            const int t = w * 16 + ln;
            bf16x8 afr = *(const bf16x8*)(X + xbase + (size_t)t * E_ + p * 256 + eo);
#pragma unroll
            for (int j = 0; j < 4; j++)
                acc[j] = __builtin_amdgcn_mfma_f32_16x16x32_bf16(afr, bfr[j], acc[j], 0, 0, 0);
        }
    }
    // epilogue: H[b][d][t] = acc + freq[t][d] + b_in[d], float4 store along t
#pragma unroll
    for (int j = 0; j < 4; j++) {
        int d  = d0 + j * 16 + ln;
        int tb = t0 + w * 16 + q * 4;
        float bi = ldin(b_in, d, fl);
        f32x4 o;
#pragma unroll
        for (int r4 = 0; r4 < 4; r4++)
            o[r4] = acc[j][r4] + ldin(freq, (tb + r4) * D_ + d, fl) + bi;
        *(f32x4*)(H + ((size_t)b * D_ + d) * T_ + tb) = o;
    }
}

// ---------------- fused 4-layer S4 scan: 2 waves = ONE (b,d) row, n-SPLIT ----------------
// R21: s4 plateaued 40-44 µs across TCH splits — the seesaw: splitting TIME
// duplicates KS+params per extra wave. The 16 n-states are embarrassingly
// parallel (only coupling: y = sum_n CB*z). Split n instead: wave w owns
// n in [8w,8w+8) -> pass1/KS/pass2 ALL halve per wave, nothing duplicated;
// 2048 blocks x 2 waves = 4096 waves = 4 waves/SIMD (2x occupancy).
// Coupling: per-(lane,j) partial y-sums exchanged via LDS xch[j][lane][w]
// (16KB, 8 blocks/CU = 128KB <= 160); both waves read the b64 pair and
// redundantly compute gelu+residual (bit-identical both sides: pr[0]+pr[1]
// same rounding) so no u-exchange; 2 barriers/layer; store gated on w==0.
// VGPR peak ~85 (no sp[] array - own partial read back from LDS) -> (128,4)
// cap 128 is safe. L1 param sharing kept: d = bid>>2 (4 blocks share d).
__global__ __launch_bounds__(128, 4)
void s4_kernel(float* __restrict__ H, const float* __restrict__ P,
               const float* __restrict__ P2, const float* __restrict__ PW) {
    __shared__ float xch[32][64][2];          // [j][lane][wave] partial y-sums
    const int w = threadIdx.x >> 6, lane = threadIdx.x & 63;
    const int d = blockIdx.x >> 2, b = blockIdx.x & 3;
    const int row = b * D_ + d;
    const int no = w << 3;                    // n-offset (floats): wave's 4 f32x2
    float* gp = H + (size_t)row * T_ + lane * TCH;

    // ---- entry: lane's contiguous 32 floats -> registers (8x f32x4) ----
    float u[TCH];
#pragma unroll
    for (int k = 0; k < TCH / 4; k++) {
        f32x4 v = *(const f32x4*)(gp + k * 4);
        u[k * 4] = v[0]; u[k * 4 + 1] = v[1]; u[k * 4 + 2] = v[2]; u[k * 4 + 3] = v[3];
    }

    for (int l = 0; l < L_; ++l) {
        const float* pp  = P2 + (size_t)((l << 9) + d) * 32 + no;
        const float* pwt = PW + (((size_t)((l << 9) + d)) << 10) + no;
        // ---- pass1: z'-space chunk sums from zero: b = Ab*b + u (4 states) ----
        f32x2 bb[4];
#pragma unroll
        for (int n = 0; n < 4; n++) { bb[n][0] = 0.f; bb[n][1] = 0.f; }
        f32x2 Ab[4];
#pragma unroll
        for (int n = 0; n < 4; n++) Ab[n] = *(const f32x2*)(pp + 2 * n);
#pragma unroll
        for (int j = 0; j < TCH; j++) {
            f32x2 u2; u2[0] = u[j]; u2[1] = u[j];
#pragma unroll
            for (int n = 0; n < 4; n++) bb[n] = pk_fma(Ab[n], bb[n], u2);
        }
        // ---- Kogge-Stone across 64 lanes (chunk decay M = Ab^32, weights from PW) ----
        {
            f32x2 W[4];
#pragma unroll
            for (int n = 0; n < 4; n++) W[n] = *(const f32x2*)(pwt + 16 + 2 * n);    // M^1
#pragma unroll
            for (int n = 0; n < 4; n++) bb[n] = pk_fma(W[n], mdpp2<0x111>(bb[n]), bb[n]);
#pragma unroll
            for (int n = 0; n < 4; n++) W[n] = *(const f32x2*)(pwt + 32 + 2 * n);    // M^2
#pragma unroll
            for (int n = 0; n < 4; n++) bb[n] = pk_fma(W[n], mdpp2<0x112>(bb[n]), bb[n]);
#pragma unroll
            for (int n = 0; n < 4; n++) W[n] = *(const f32x2*)(pwt + 64 + 2 * n);    // M^4
#pragma unroll
            for (int n = 0; n < 4; n++) bb[n] = pk_fma(W[n], mdpp2<0x114>(bb[n]), bb[n]);
#pragma unroll
            for (int n = 0; n < 4; n++) W[n] = *(const f32x2*)(pwt + 128 + 2 * n);   // M^8
#pragma unroll
            for (int n = 0; n < 4; n++) bb[n] = pk_fma(W[n], mdpp2<0x118>(bb[n]), bb[n]);
        }
        {
            f32x2 w1[4];
            const float* p1 = pwt + (((lane & 15) + 1) << 4);
#pragma unroll
            for (int n = 0; n < 4; n++) w1[n] = *(const f32x2*)(p1 + 2 * n);         // M^((lane&15)+1)
#pragma unroll
            for (int n = 0; n < 4; n++) bb[n] = pk_fma(w1[n], dpp2<0x142, 0xA>(bb[n]), bb[n]);
        }
        {
            f32x2 w2[4];
            const float* p2_ = pwt + (((lane & 31) + 1) << 4);
#pragma unroll
            for (int n = 0; n < 4; n++) w2[n] = *(const f32x2*)(p2_ + 2 * n);        // M^((lane&31)+1)
#pragma unroll
            for (int n = 0; n < 4; n++) bb[n] = pk_fma(w2[n], dpp2<0x143, 0xC>(bb[n]), bb[n]);
        }
        // ---- exclusive shift = chunk-initial z' state (wave_shr:1, lane0 -> 0) ----
        f32x2 z[4];
#pragma unroll
        for (int n = 0; n < 4; n++) z[n] = mdpp2<0x138>(bb[n]);
        // ---- pass2a: z' = Ab*z' + u; publish partial y-sum over this n-half ----
        f32x2 CB[4];
#pragma unroll
        for (int n = 0; n < 4; n++) CB[n] = *(const f32x2*)(pp + 16 + 2 * n);
#pragma unroll
        for (int j = 0; j < TCH; j++) {
            f32x2 u2; u2[0] = u[j]; u2[1] = u[j];
#pragma unroll
            for (int n = 0; n < 4; n++) z[n] = pk_fma(Ab[n], z[n], u2);
            f32x2 ya; ya[0] = 0.f; ya[1] = 0.f;
            f32x2 yb; yb[0] = 0.f; yb[1] = 0.f;
            ya = pk_fma(CB[0], z[0], ya);
            yb = pk_fma(CB[1], z[1], yb);
            ya = pk_fma(CB[2], z[2], ya);
            yb = pk_fma(CB[3], z[3], yb);
            f32x2 s = ya + yb;
            xch[j][lane][w] = s[0] + s[1];
        }
        __syncthreads();
        // ---- pass2b: y = partials + D*u; gelu; residual -> u (both waves, identical) ----
        float Dsk = P[PDSK + l * D_ + d];
#pragma unroll
        for (int j = 0; j < TCH; j++) {
            float uu = u[j];
            f32x2 pr = *(const f32x2*)(&xch[j][lane][0]);
            float y = fmaf(Dsk, uu, pr[0] + pr[1]);
            // gelu(y) = y / (1 + e^{-2*0.79788456*(y+0.044715 y^3)}); exp2-folded
            float t  = fmaf(0.044715f, y * y * y, y);
            float em = exp2f(-2.30220818f * t);          // 2*sqrt(2/pi)*log2(e)
            float r  = __builtin_amdgcn_rcpf(1.f + em);
            u[j] = fmaf(y, r, uu);                       // u + gelu(y)
        }
        __syncthreads();   // xch reused next layer
    }
    // ---- exit: registers -> lane's contiguous 32 floats (w==0 only; identical) ----
    if (w == 0) {
#pragma unroll
        for (int k = 0; k < TCH / 4; k++) {
            f32x4 v;
            v[0] = u[k * 4]; v[1] = u[k * 4 + 1]; v[2] = u[k * 4 + 2]; v[3] = u[k * 4 + 3];
            *(f32x4*)(gp + k * 4) = v;
        }
    }
}

// ---------------- final: 2x fused layernorm + projection ----------------
// R20 (kept): 256 blocks x 256 threads; 2-way d-split per lane, shfl_xor(32)
// combine, LDS cross-wave reduce.
__global__ __launch_bounds__(256) void final_kernel(const float* __restrict__ H,
                                                    const float* __restrict__ P,
                                                    void* __restrict__ out,
                                                    const void* __restrict__ lnfs_raw) {
    __shared__ float red[4][8][32];
    unsigned int f = probe_f32(lnfs_raw);
    int tid = threadIdx.x;
    int w = tid >> 6, lane = tid & 63;
    int tq = lane & 31, dp = lane >> 5;
    int tg = blockIdx.x * 32 + tq;
    int b = tg >> 11, t = tg & (T_ - 1);
    float S1=0.f,S2=0.f,Pf=0.f,Pe=0.f,Cf=0.f,Ce=0.f,Df=0.f,De=0.f;
    const float* hp = H + ((size_t)b * D_) * T_ + t;
#pragma unroll 4
    for (int k = 0; k < 64; k++) {
        int d = w * 128 + 2 * k + dp;
        float hv = hp[(size_t)d * T_];
        float sf = P[PLFS + d], bfv = P[PLFB + d], wf = P[PWF + d];
        float se = P[PLES + d], bev = P[PLEB + d], we = P[PWEN + d];
        S1 += hv; S2 = fmaf(hv, hv, S2);
        float tf = sf * wf, te = se * we;
        Pf = fmaf(hv, tf, Pf); Pe = fmaf(hv, te, Pe);
        Cf += tf; Ce += te;
        Df = fmaf(bfv, wf, Df); De = fmaf(bev, we, De);
    }
    // combine the 2 d-parities within the wave
    S1 += __shfl_xor(S1, 32); S2 += __shfl_xor(S2, 32);
    Pf += __shfl_xor(Pf, 32); Pe += __shfl_xor(Pe, 32);
    Cf += __shfl_xor(Cf, 32); Ce += __shfl_xor(Ce, 32);
    Df += __shfl_xor(Df, 32); De += __shfl_xor(De, 32);
    if (dp == 0) {
        red[w][0][tq]=S1; red[w][1][tq]=S2; red[w][2][tq]=Pf; red[w][3][tq]=Pe;
        red[w][4][tq]=Cf; red[w][5][tq]=Ce; red[w][6][tq]=Df; red[w][7][tq]=De;
    }
    __syncthreads();
    if (tid < 32) {
        float a[8];
#pragma unroll
        for (int k = 0; k < 8; k++)
            a[k] = red[0][k][tid] + red[1][k][tid] + red[2][k][tid] + red[3][k][tid];
        float mu  = a[0] * (1.f / 512.f);
        float var = a[1] * (1.f / 512.f) - mu * mu;
        float r   = rsqrtf(var + 1e-5f);
        float f0  = r * (a[2] - mu * a[4]) + a[6] + P[PSC + 0];
        float en  = r * (a[3] - mu * a[5]) + a[7] + P[PSC + 1];
        int tg2 = blockIdx.x * 32 + tid;
        if (f) {
            ((float*)out)[tg2]           = f0;
            ((float*)out)[B_ * T_ + tg2] = en;
        } else {
            ((unsigned short*)out)[tg2]           = f2us(f0);
            ((unsigned short*)out)[B_ * T_ + tg2] = f2us(en);
        }
    }
}

extern "C" void kernel_launch(void* const* d_in, const int* in_sizes, int n_in,
                              void* d_out, int out_size, void* d_ws, size_t ws_size,
                              hipStream_t stream) {
    (void)in_sizes; (void)n_in; (void)out_size; (void)ws_size;
    float* ws = (float*)d_ws;
    float* P     = ws;                                      // 105,504 slots (105,474 used)
    float* H     = ws + 105504;                             // 4,194,304
    unsigned short* textc = (unsigned short*)(ws + 4299808);// 4,194,304 bf16 (2,097,152 slots)
    unsigned short* Wt    = (unsigned short*)(ws + 6396960);// 262,144 bf16 (131,072 slots)
    float* P2    = ws + 6528032;                            // L*D*32 = 65,536 floats
    float* PW    = ws + 6593568;                            // L*D*64*16 = 2,097,152 floats (M=Ab^32 powers)
    // total: 8,690,720 floats = 34.8 MB

    prep_kernel<<<dim3(NB_TEXT + NB_PRM + NB_WT + NB_S4P), dim3(256), 0, stream>>>(
        d_in[0], d_in[1], d_in[4], d_in[5], d_in[6], d_in[7], d_in[8],
        d_in[9], d_in[10], d_in[11], d_in[13], d_in[14], d_in[15],
        d_in[12], d_in[16], textc, Wt, P, P2, PW);
    gemm_kernel<<<dim3(8, 32, 4), dim3(256), 0, stream>>>(textc, Wt, d_in[3], d_in[2], d_in[9], H);
    s4_kernel<<<dim3(2048), dim3(128), 0, stream>>>(H, P, P2, PW);
    final_kernel<<<dim3(256), dim3(256), 0, stream>>>(H, P, d_out, d_in[9]);
}

// Round 10
// 160.984 us; speedup vs baseline: 1.1373x; 1.1373x over previous
//
#include <hip/hip_runtime.h>

#define B_   4
#define T_   2048
#define E_   512
#define D_   512
#define N_   16
#define L_   4
#define TCH  32          // elements per lane — ONE wave owns a full (b,d) row

typedef __bf16 bf16x8 __attribute__((ext_vector_type(8)));
typedef float  f32x4  __attribute__((ext_vector_type(4)));
typedef float  f32x2  __attribute__((ext_vector_type(2)));
typedef unsigned short us8 __attribute__((ext_vector_type(8)));

__device__ __forceinline__ float us2f(unsigned short u) {
    return __uint_as_float(((unsigned int)u) << 16);
}
__device__ __forceinline__ unsigned short f2us(float f) {
    unsigned int u = __float_as_uint(f);
    unsigned int r = (u + 0x7fffu + ((u >> 16) & 1u)) >> 16;   // RNE
    return (unsigned short)r;
}
__device__ __forceinline__ float ldin(const void* p, int i, unsigned int f) {
    return f ? ((const float*)p)[i] : us2f(((const unsigned short*)p)[i]);
}
__device__ __forceinline__ unsigned int probe_f32(const void* lnfs) {
    return (((const unsigned int*)lnfs)[0] == 0x3F800000u) ? 1u : 0u;
}
__device__ __forceinline__ f32x2 pk_fma(f32x2 a, f32x2 b, f32x2 c) {
    f32x2 d;
    asm("v_pk_fma_f32 %0, %1, %2, %3" : "=v"(d) : "v"(a), "v"(b), "v"(c));
    return d;
}
// masked-row DPP (0x142/0x143): masked lanes must yield 0 for the fma — old=0 form
template<int CTRL, int RM>
__device__ __forceinline__ f32x2 dpp2(f32x2 v) {
    f32x2 r;
    r[0] = __int_as_float(__builtin_amdgcn_update_dpp(0, __float_as_int(v[0]), CTRL, RM, 0xF, true));
    r[1] = __int_as_float(__builtin_amdgcn_update_dpp(0, __float_as_int(v[1]), CTRL, RM, 0xF, true));
    return r;
}
// full-mask DPP: single v_mov_b32_dpp, bound_ctrl zero-fills invalid lanes
template<int CTRL>
__device__ __forceinline__ f32x2 mdpp2(f32x2 v) {
    f32x2 r;
    r[0] = __int_as_float(__builtin_amdgcn_mov_dpp(__float_as_int(v[0]), CTRL, 0xF, 0xF, true));
    r[1] = __int_as_float(__builtin_amdgcn_mov_dpp(__float_as_int(v[1]), CTRL, 0xF, 0xF, true));
    return r;
}

// canonical param block offsets (floats)
#define PA    0
#define PB    32768
#define PC    65536
#define PDT   98304
#define PDSK  100352
#define PLFS  102400
#define PLFB  102912
#define PWF   103424
#define PLES  103936
#define PLEB  104448
#define PWEN  104960
#define PSC   105472   // [0]=b_f0, [1]=b_en
#define PTF   105474   // tf[d] = ln_f0_scale[d]*W_f0[d]  (512)
#define PTE   105986   // te[d] = ln_en_scale[d]*W_en[d]  (512)
#define PS2   106498   // [Cf, Ce, Df, De] h-independent LN sums

#define NB_TEXT 2048
#define NB_PRM  413       // ceil(105474/256)
#define NB_WT   64        // 8x8 tiles of 64x64
#define NB_S4P  128       // L*D*N/256 — precomputed scan params
// +1 trailing block: tf/te tables + LN scalar reduction

// ---------------- prep: text->bf16, params->fp32 P, Wt transpose, S4 precompute, LN precompute ----------------
__global__ __launch_bounds__(256) void prep_kernel(
    const void* X, const void* Win,
    const void* A_log, const void* B_ssm, const void* C_ssm,
    const void* log_dt, const void* D_skip,
    const void* lnfs, const void* lnfb, const void* Wf0,
    const void* lnes, const void* lneb, const void* Wen,
    const void* bf0, const void* ben,
    unsigned short* __restrict__ textc, unsigned short* __restrict__ Wt,
    float* __restrict__ P, float* __restrict__ P2, float* __restrict__ PW) {
    __shared__ float tile[64 * 65];
    unsigned int f = probe_f32(lnfs);
    int bid = blockIdx.x;
    if (bid < NB_TEXT) {
        int i = (bid * 256 + threadIdx.x) * 8;
        if (f) {
            const float* xf = (const float*)X;
            us8 r;
#pragma unroll
            for (int j = 0; j < 8; j++) r[j] = f2us(xf[i + j]);
            *(us8*)(textc + i) = r;
        } else {
            *(us8*)(textc + i) = *(const us8*)((const unsigned short*)X + i);
        }
    } else if (bid < NB_TEXT + NB_PRM) {
        int i = (bid - NB_TEXT) * 256 + threadIdx.x;
        if      (i < PB)     P[i] = ldin(A_log,  i - PA,   f);
        else if (i < PC)     P[i] = ldin(B_ssm,  i - PB,   f);
        else if (i < PDT)    P[i] = ldin(C_ssm,  i - PC,   f);
        else if (i < PDSK)   P[i] = ldin(log_dt, i - PDT,  f);
        else if (i < PLFS)   P[i] = ldin(D_skip, i - PDSK, f);
        else if (i < PLFB)   P[i] = ldin(lnfs,   i - PLFS, f);
        else if (i < PWF)    P[i] = ldin(lnfb,   i - PLFB, f);
        else if (i < PLES)   P[i] = ldin(Wf0,    i - PWF,  f);
        else if (i < PLEB)   P[i] = ldin(lnes,   i - PLES, f);
        else if (i < PWEN)   P[i] = ldin(lneb,   i - PLEB, f);
        else if (i < PSC)    P[i] = ldin(Wen,    i - PWEN, f);
        else if (i == PSC)     P[i] = ldin(bf0, 0, f);
        else if (i == PSC + 1) P[i] = ldin(ben, 0, f);
    } else if (bid < NB_TEXT + NB_PRM + NB_WT) {
        // Wt[d][e] = W_in[e][d]  (bf16 out), 64x64 LDS tile
        int tb = bid - (NB_TEXT + NB_PRM);
        int d0 = (tb >> 3) * 64, e0 = (tb & 7) * 64;
        int r = threadIdx.x >> 6, i = threadIdx.x & 63;
#pragma unroll
        for (int k = 0; k < 16; k++) {
            int e = k * 4 + r;
            tile[e * 65 + i] = ldin(Win, (e0 + e) * D_ + d0 + i, f);
        }
        __syncthreads();
#pragma unroll
        for (int k = 0; k < 16; k++) {
            int dd = k * 4 + r;
            Wt[(size_t)(d0 + dd) * E_ + e0 + i] = f2us(tile[i * 65 + dd]);
        }
    } else if (bid < NB_TEXT + NB_PRM + NB_WT + NB_S4P) {
        // S4 param precompute: i indexes (l,d,n); per (l,d) P2 layout (stride 32):
        //   [Ab16 | CB16]
        // Chunk length 32 (one lane owns 32 t) -> M = Ab^32.
        // PW power table: PW[ld*1024 + k*16 + n] = M^k. s4 only reads k<=32.
        int i = (bid - (NB_TEXT + NB_PRM + NB_WT)) * 256 + threadIdx.x;   // [0, L*D*N)
        int n = i & 15;
        int ld = i >> 4;                       // l*512 + d
        float dt = __expf(ldin(log_dt, ld, f));
        float A  = -__expf(ldin(A_log, i, f));
        float Ab = __expf(dt * A);
        float Bb = (Ab - 1.f) / A * ldin(B_ssm, i, f);
        float l2M = 46.166241308446827f * dt * A;   // log2(Ab^32) = 32*dt*A/ln2
        float M   = exp2f(l2M);                     // M = Ab^32
        int base = ld * 32 + n;
        P2[base]      = Ab;
        P2[base + 16] = Bb * ldin(C_ssm, i, f);     // CB
        float pw = 1.f;
        size_t pb = ((size_t)ld << 10) + n;
#pragma unroll
        for (int k = 0; k < 33; k++) { PW[pb + (k << 4)] = pw; pw *= M; }
    } else {
        // R22: LN precompute — tf/te per-d tables + the 4 h-independent scalar
        // sums (Cf = sum tf, Ce = sum te, Df = sum bf*wf, De = sum be*we),
        // hoisted out of final_kernel's per-(b,t) inner loop.
        int tid = threadIdx.x;
        float cf = 0.f, ce = 0.f, df = 0.f, de = 0.f;
#pragma unroll
        for (int k = 0; k < 2; k++) {
            int d = k * 256 + tid;
            float wf = ldin(Wf0, d, f), we = ldin(Wen, d, f);
            float tf = ldin(lnfs, d, f) * wf, te = ldin(lnes, d, f) * we;
            P[PTF + d] = tf;  P[PTE + d] = te;
            cf += tf; ce += te;
            df = fmaf(ldin(lnfb, d, f), wf, df);
            de = fmaf(ldin(lneb, d, f), we, de);
        }
        tile[tid] = cf; tile[256 + tid] = ce; tile[512 + tid] = df; tile[768 + tid] = de;
        __syncthreads();
        for (int s = 128; s >= 1; s >>= 1) {
            if (tid < s) {
                tile[tid]       += tile[tid + s];
                tile[256 + tid] += tile[256 + tid + s];
                tile[512 + tid] += tile[512 + tid + s];
                tile[768 + tid] += tile[768 + tid + s];
            }
            __syncthreads();
        }
        if (tid == 0) {
            P[PS2 + 0] = tile[0];   P[PS2 + 1] = tile[256];
            P[PS2 + 2] = tile[512]; P[PS2 + 3] = tile[768];
        }
    }
}

// ---------------- GEMM: H[b][d][t] = sum_e X[b][t][e]*W_in[e][d] + freq[t][d] + b_in[d] ----------------
// R20: 64x64 tiles, 1024 blocks = 4 blocks/CU = 4 waves/SIMD.
// R22: XCD-aware remap. Default x-fastest dispatch round-robins consecutive
// blocks (the 8 d0-tiles sharing one X-tile) across the 8 XCDs -> X fetched
// ~8x from HBM (~64MB). Remap so XCD c owns t0-tiles [4c,4c+4) for all (d0,b):
// per-XCD set = X 1MB + W 0.5MB + freq 0.5MB, all L2-resident; X HBM 8MB.
__global__ __launch_bounds__(256) void gemm_kernel(const unsigned short* __restrict__ X,
                                                   const unsigned short* __restrict__ Wt,
                                                   const void* __restrict__ freq,
                                                   const void* __restrict__ b_in,
                                                   const void* __restrict__ lnfs,
                                                   float* __restrict__ H) {
    __shared__ unsigned short wlds[64 * 264];
    const unsigned int fl = probe_f32(lnfs);
    const int tid = threadIdx.x;
    const int w  = tid >> 6;
    const int ln = tid & 15;
    const int q  = (tid >> 4) & 3;
    // XCD chunked remap: lid x-fastest; xcd = lid>>7 owns a contiguous 128-block chunk
    const int lid = blockIdx.x + 8 * (blockIdx.y + 32 * blockIdx.z);
    const int xcd = lid >> 7, wi = lid & 127;
    const int d0 = (wi & 7) * 64;
    const int t0 = ((xcd << 2) + ((wi >> 3) & 3)) * 64;
    const int b  = wi >> 5;

    f32x4 acc[4];
#pragma unroll
    for (int j = 0; j < 4; j++) { acc[j][0]=0.f; acc[j][1]=0.f; acc[j][2]=0.f; acc[j][3]=0.f; }

    const size_t xbase = ((size_t)b * T_ + t0) * E_;

#pragma unroll
    for (int p = 0; p < 2; ++p) {
        if (p) __syncthreads();
#pragma unroll
        for (int it = 0; it < 8; ++it) {
            int flat = it * 256 + tid;
            int d = flat >> 5;
            int e = (flat & 31) << 3;
            bf16x8 v = *(const bf16x8*)(Wt + (size_t)(d0 + d) * E_ + p * 256 + e);
            *(bf16x8*)(wlds + d * 264 + e) = v;
        }
        __syncthreads();
#pragma unroll
        for (int s = 0; s < 8; ++s) {
            const int eo = s * 32 + q * 8;
            bf16x8 bfr[4];
#pragma unroll
            for (int j = 0; j < 4; j++)
                bfr[j] = *(const bf16x8*)(wlds + (j * 16 + ln) * 264 + eo);
            const int t = w * 16 + ln;
            bf16x8 afr = *(const bf16x8*)(X + xbase + (size_t)t * E_ + p * 256 + eo);
#pragma unroll
            for (int j = 0; j < 4; j++)
                acc[j] = __builtin_amdgcn_mfma_f32_16x16x32_bf16(afr, bfr[j], acc[j], 0, 0, 0);
        }
    }
    // epilogue: H[b][d][t] = acc + freq[t][d] + b_in[d], float4 store along t
#pragma unroll
    for (int j = 0; j < 4; j++) {
        int d  = d0 + j * 16 + ln;
        int tb = t0 + w * 16 + q * 4;
        float bi = ldin(b_in, d, fl);
        f32x4 o;
#pragma unroll
        for (int r4 = 0; r4 < 4; r4++)
            o[r4] = acc[j][r4] + ldin(freq, (tb + r4) * D_ + d, fl) + bi;
        *(f32x4*)(H + ((size_t)b * D_ + d) * T_ + tb) = o;
    }
}

// ---------------- fused 4-layer S4 scan: ONE wave = ONE (b,d) row, TCH=32 ----------------
// R22: reverted to the best-measured R19 form (<=42.6 µs). R21's n-split
// regressed to 61.9 µs: 1M LDS bank conflicts (xch stride-2), double H fetch,
// 2 barriers/layer — coupling cost > halved compute. s4 is at a structural
// plateau (TCH 16/32, n-split all 40-62 µs); block = same d across 4 batches
// (d = bid, row = w*512 + d) keeps params L1-shared across the 4 waves.
__global__ __launch_bounds__(256, 2)
void s4_kernel(float* __restrict__ H, const float* __restrict__ P,
               const float* __restrict__ P2, const float* __restrict__ PW) {
    const int w = threadIdx.x >> 6, lane = threadIdx.x & 63;
    const int d = blockIdx.x;                 // block owns one d; waves = batches
    const int row = w * D_ + d;               // row = b*512 + d with b = w
    float* gp = H + (size_t)row * T_ + lane * TCH;

    // ---- entry: lane's contiguous 32 floats -> registers (8x f32x4) ----
    float u[TCH];
#pragma unroll
    for (int k = 0; k < TCH / 4; k++) {
        f32x4 v = *(const f32x4*)(gp + k * 4);
        u[k * 4] = v[0]; u[k * 4 + 1] = v[1]; u[k * 4 + 2] = v[2]; u[k * 4 + 3] = v[3];
    }

    for (int l = 0; l < L_; ++l) {
        const float* pp  = P2 + (size_t)((l << 9) + d) * 32;
        const float* pwt = PW + ((size_t)((l << 9) + d) << 10);
        // ---- pass1: z'-space chunk sums from zero: b = Ab*b + u ----
        f32x2 b[8];
#pragma unroll
        for (int n = 0; n < 8; n++) { b[n][0] = 0.f; b[n][1] = 0.f; }
        {
            f32x2 Ab[8];
#pragma unroll
            for (int n = 0; n < 8; n++) Ab[n] = *(const f32x2*)(pp + 2 * n);
#pragma unroll
            for (int j = 0; j < TCH; j++) {
                f32x2 u2; u2[0] = u[j]; u2[1] = u[j];
#pragma unroll
                for (int n = 0; n < 8; n++) b[n] = pk_fma(Ab[n], b[n], u2);
            }
        }
        // ---- Kogge-Stone across 64 lanes (chunk decay M = Ab^32, weights from PW) ----
        {
            f32x2 W[8];
#pragma unroll
            for (int n = 0; n < 8; n++) W[n] = *(const f32x2*)(pwt + 16 + 2 * n);    // M^1
#pragma unroll
            for (int n = 0; n < 8; n++) b[n] = pk_fma(W[n], mdpp2<0x111>(b[n]), b[n]);
#pragma unroll
            for (int n = 0; n < 8; n++) W[n] = *(const f32x2*)(pwt + 32 + 2 * n);    // M^2
#pragma unroll
            for (int n = 0; n < 8; n++) b[n] = pk_fma(W[n], mdpp2<0x112>(b[n]), b[n]);
#pragma unroll
            for (int n = 0; n < 8; n++) W[n] = *(const f32x2*)(pwt + 64 + 2 * n);    // M^4
#pragma unroll
            for (int n = 0; n < 8; n++) b[n] = pk_fma(W[n], mdpp2<0x114>(b[n]), b[n]);
#pragma unroll
            for (int n = 0; n < 8; n++) W[n] = *(const f32x2*)(pwt + 128 + 2 * n);   // M^8
#pragma unroll
            for (int n = 0; n < 8; n++) b[n] = pk_fma(W[n], mdpp2<0x118>(b[n]), b[n]);
        }
        {
            f32x2 w1[8];
            const float* p1 = pwt + (((lane & 15) + 1) << 4);
#pragma unroll
            for (int n = 0; n < 8; n++) w1[n] = *(const f32x2*)(p1 + 2 * n);         // M^((lane&15)+1)
#pragma unroll
            for (int n = 0; n < 8; n++) b[n] = pk_fma(w1[n], dpp2<0x142, 0xA>(b[n]), b[n]);
        }
        {
            f32x2 w2[8];
            const float* p2_ = pwt + (((lane & 31) + 1) << 4);
#pragma unroll
            for (int n = 0; n < 8; n++) w2[n] = *(const f32x2*)(p2_ + 2 * n);        // M^((lane&31)+1)
#pragma unroll
            for (int n = 0; n < 8; n++) b[n] = pk_fma(w2[n], dpp2<0x143, 0xC>(b[n]), b[n]);
        }
        // ---- exclusive shift = chunk-initial z' state (wave_shr:1, lane0 -> 0) ----
        f32x2 z[8];
#pragma unroll
        for (int n = 0; n < 8; n++) z[n] = mdpp2<0x138>(b[n]);
        // ---- pass2: z' = Ab*z' + u; y = sum(CB*z') + D*u; gelu; residual -> u ----
        float Dsk = P[PDSK + l * D_ + d];
        f32x2 Ab[8], CB[8];
#pragma unroll
        for (int n = 0; n < 8; n++) Ab[n] = *(const f32x2*)(pp + 2 * n);
#pragma unroll
        for (int n = 0; n < 8; n++) CB[n] = *(const f32x2*)(pp + 16 + 2 * n);
#pragma unroll
        for (int j = 0; j < TCH; j++) {
            float uu = u[j];
            f32x2 u2; u2[0] = uu; u2[1] = uu;
#pragma unroll
            for (int n = 0; n < 8; n++) z[n] = pk_fma(Ab[n], z[n], u2);
            f32x2 ya; ya[0] = 0.f; ya[1] = 0.f;
            f32x2 yb; yb[0] = 0.f; yb[1] = 0.f;
#pragma unroll
            for (int n = 0; n < 8; n += 2) {
                ya = pk_fma(CB[n], z[n], ya);
                yb = pk_fma(CB[n + 1], z[n + 1], yb);
            }
            f32x2 s = ya + yb;
            float y = fmaf(Dsk, uu, s[0] + s[1]);
            // gelu(y) = y / (1 + e^{-2*0.79788456*(y+0.044715 y^3)}); exp2-folded
            float t  = fmaf(0.044715f, y * y * y, y);
            float em = exp2f(-2.30220818f * t);          // 2*sqrt(2/pi)*log2(e)
            float r  = __builtin_amdgcn_rcpf(1.f + em);
            u[j] = fmaf(y, r, uu);                       // u + gelu(y)
        }
    }
    // ---- exit: registers -> lane's contiguous 32 floats (8x f32x4) ----
#pragma unroll
    for (int k = 0; k < TCH / 4; k++) {
        f32x4 v;
        v[0] = u[k * 4]; v[1] = u[k * 4 + 1]; v[2] = u[k * 4 + 2]; v[3] = u[k * 4 + 3];
        *(f32x4*)(gp + k * 4) = v;
    }
}

// ---------------- final: 2x fused layernorm + projection ----------------
// R20: 256 blocks x 256 threads; 2-way d-split per lane, shfl_xor(32) combine.
// R22: inner loop slimmed via prep-hoisted tf/te tables and PS2 scalars:
// 3 loads + 4 FMAs per d (was 7 loads + 8 FMAs).
__global__ __launch_bounds__(256) void final_kernel(const float* __restrict__ H,
                                                    const float* __restrict__ P,
                                                    void* __restrict__ out,
                                                    const void* __restrict__ lnfs_raw) {
    __shared__ float red[4][4][32];
    unsigned int f = probe_f32(lnfs_raw);
    int tid = threadIdx.x;
    int w = tid >> 6, lane = tid & 63;
    int tq = lane & 31, dp = lane >> 5;
    int tg = blockIdx.x * 32 + tq;
    int b = tg >> 11, t = tg & (T_ - 1);
    float S1 = 0.f, S2 = 0.f, Pf = 0.f, Pe = 0.f;
    const float* hp = H + ((size_t)b * D_) * T_ + t;
#pragma unroll 4
    for (int k = 0; k < 64; k++) {
        int d = w * 128 + 2 * k + dp;
        float hv = hp[(size_t)d * T_];
        float tf = P[PTF + d], te = P[PTE + d];
        S1 += hv; S2 = fmaf(hv, hv, S2);
        Pf = fmaf(hv, tf, Pf); Pe = fmaf(hv, te, Pe);
    }
    // combine the 2 d-parities within the wave
    S1 += __shfl_xor(S1, 32); S2 += __shfl_xor(S2, 32);
    Pf += __shfl_xor(Pf, 32); Pe += __shfl_xor(Pe, 32);
    if (dp == 0) {
        red[w][0][tq] = S1; red[w][1][tq] = S2; red[w][2][tq] = Pf; red[w][3][tq] = Pe;
    }
    __syncthreads();
    if (tid < 32) {
        float a[4];
#pragma unroll
        for (int k = 0; k < 4; k++)
            a[k] = red[0][k][tid] + red[1][k][tid] + red[2][k][tid] + red[3][k][tid];
        float mu  = a[0] * (1.f / 512.f);
        float var = a[1] * (1.f / 512.f) - mu * mu;
        float r   = rsqrtf(var + 1e-5f);
        float f0  = r * (a[2] - mu * P[PS2 + 0]) + P[PS2 + 2] + P[PSC + 0];
        float en  = r * (a[3] - mu * P[PS2 + 1]) + P[PS2 + 3] + P[PSC + 1];
        int tg2 = blockIdx.x * 32 + tid;
        if (f) {
            ((float*)out)[tg2]           = f0;
            ((float*)out)[B_ * T_ + tg2] = en;
        } else {
            ((unsigned short*)out)[tg2]           = f2us(f0);
            ((unsigned short*)out)[B_ * T_ + tg2] = f2us(en);
        }
    }
}

extern "C" void kernel_launch(void* const* d_in, const int* in_sizes, int n_in,
                              void* d_out, int out_size, void* d_ws, size_t ws_size,
                              hipStream_t stream) {
    (void)in_sizes; (void)n_in; (void)out_size; (void)ws_size;
    float* ws = (float*)d_ws;
    float* P     = ws;                                      // 106,528 slots (106,502 used)
    float* H     = ws + 106528;                             // 4,194,304
    unsigned short* textc = (unsigned short*)(ws + 4300832);// 4,194,304 bf16 (2,097,152 slots)
    unsigned short* Wt    = (unsigned short*)(ws + 6397984);// 262,144 bf16 (131,072 slots)
    float* P2    = ws + 6529056;                            // L*D*32 = 65,536 floats
    float* PW    = ws + 6594592;                            // L*D*64*16 = 2,097,152 floats (M=Ab^32 powers)
    // total: 8,691,744 floats = 34.8 MB

    prep_kernel<<<dim3(NB_TEXT + NB_PRM + NB_WT + NB_S4P + 1), dim3(256), 0, stream>>>(
        d_in[0], d_in[1], d_in[4], d_in[5], d_in[6], d_in[7], d_in[8],
        d_in[9], d_in[10], d_in[11], d_in[13], d_in[14], d_in[15],
        d_in[12], d_in[16], textc, Wt, P, P2, PW);
    gemm_kernel<<<dim3(8, 32, 4), dim3(256), 0, stream>>>(textc, Wt, d_in[3], d_in[2], d_in[9], H);
    s4_kernel<<<dim3(512), dim3(256), 0, stream>>>(H, P, P2, PW);
    final_kernel<<<dim3(256), dim3(256), 0, stream>>>(H, P, d_out, d_in[9]);
}